// Round 4
// baseline (3167.461 us; speedup 1.0000x reference)
//
#include <hip/hip_runtime.h>
#include <math.h>

#define S_LEN 4096
#define HDIM  64
#define WTOK  256      // attention window w
#define WIN   513      // 2w+1
#define NBH   32       // B*H

static constexpr size_t CTX_ELEMS = (size_t)NBH * S_LEN * HDIM;  // 8388608

// ---------------------------------------------------------------------------
// Kernel A: banded QK^T + softmax, writes attn_probs [NBH][S][513].
// grid = NBH * (S/32) = 4096 blocks, 256 threads (4 waves), 8 rows/wave.
// acc[8][9]: lane owns absolute key column; 9 tiles of 64 keys cover the
// 520-wide union of 8 rows' windows. VGPR budget ~125 under the
// __launch_bounds__(256,4) cap -> 4 waves/SIMD for latency hiding.
// K is read direct from global via 9 clamped byte-offsets + imm offsets
// (d4*16 folds into the load); per-tile 16KB working set stays L1-hot.
// ---------------------------------------------------------------------------
__global__ __launch_bounds__(256, 4) void qk_softmax_probs(
    const float* __restrict__ q, const float* __restrict__ k,
    float* __restrict__ probs)
{
    __shared__ float qs[32 * HDIM];   // 8 KB Q tile

    const int bid  = blockIdx.x;
    const int bh   = bid >> 7;
    const int q0   = (bid & 127) << 5;   // 32 query rows per block
    const int tid  = threadIdx.x;
    const int lane = tid & 63;
    const int wave = tid >> 6;

    const size_t bh_base = (size_t)bh * S_LEN * HDIM;

    // stage Q tile (coalesced float4)
    {
        const float4* src = reinterpret_cast<const float4*>(q + bh_base + (size_t)q0 * HDIM);
        float4* dst = reinterpret_cast<float4*>(qs);
        dst[tid]       = src[tid];
        dst[tid + 256] = src[tid + 256];
    }
    __syncthreads();

    const int qr0     = q0 + wave * 8;          // wave's 8-row group
    const int keybase = qr0 - WTOK + lane;      // lane's key for tile 0
    const char* kbase = reinterpret_cast<const char*>(k + bh_base);

    int koff[9];
    #pragma unroll
    for (int t = 0; t < 9; ++t) {
        int kc = min(max(keybase + t * 64, 0), S_LEN - 1);
        koff[t] = kc << 8;   // byte offset (256 B per K row)
    }

    float acc[8][9];
    #pragma unroll
    for (int rr = 0; rr < 8; ++rr)
        #pragma unroll
        for (int t = 0; t < 9; ++t) acc[rr][t] = 0.0f;

    const int qrow0 = wave * 8;

    #pragma unroll 4
    for (int d4 = 0; d4 < 16; ++d4) {
        float4 qv[8];
        #pragma unroll
        for (int rr = 0; rr < 8; ++rr)
            qv[rr] = *reinterpret_cast<const float4*>(&qs[(qrow0 + rr) * HDIM + d4 * 4]);
        #pragma unroll
        for (int t = 0; t < 9; ++t) {
            float4 kv = *reinterpret_cast<const float4*>(kbase + koff[t] + d4 * 16);
            #pragma unroll
            for (int rr = 0; rr < 8; ++rr) {
                acc[rr][t] = fmaf(qv[rr].x, kv.x, acc[rr][t]);
                acc[rr][t] = fmaf(qv[rr].y, kv.y, acc[rr][t]);
                acc[rr][t] = fmaf(qv[rr].z, kv.z, acc[rr][t]);
                acc[rr][t] = fmaf(qv[rr].w, kv.w, acc[rr][t]);
            }
        }
    }

    const float scale = 0.125f;   // 1/sqrt(64)

    #pragma unroll
    for (int rr = 0; rr < 8; ++rr) {
        float s[9];
        float m = -INFINITY;
        #pragma unroll
        for (int t = 0; t < 9; ++t) {
            int key = keybase + t * 64;
            int j   = t * 64 + lane - rr;
            bool ok = (key >= 0) && (key < S_LEN) && (j >= 0) && (j <= 2 * WTOK);
            s[t] = ok ? acc[rr][t] * scale : -INFINITY;
            m = fmaxf(m, s[t]);
        }
        #pragma unroll
        for (int off = 32; off > 0; off >>= 1)
            m = fmaxf(m, __shfl_xor(m, off, 64));

        float z = 0.0f;
        #pragma unroll
        for (int t = 0; t < 9; ++t) {
            s[t] = __expf(s[t] - m);   // exp(-inf)=0 for masked entries
            z += s[t];
        }
        #pragma unroll
        for (int off = 32; off > 0; off >>= 1)
            z += __shfl_xor(z, off, 64);
        float inv = 1.0f / z;

        size_t base = ((size_t)bh * S_LEN + (qr0 + rr)) * WIN;
        #pragma unroll
        for (int t = 0; t < 9; ++t) {
            int j = t * 64 + lane - rr;
            if (j >= 0 && j <= 2 * WTOK)
                probs[base + j] = s[t] * inv;
        }
    }
}

// ---------------------------------------------------------------------------
// Kernel B: banded PV. context[row][d] = sum_j probs[row][j] * v[row-256+j][d]
// grid = NBH * (S/64) = 2048 blocks, 256 threads (4 waves), 16 rows/wave,
// acc[2][8] = 16 VGPRs -> high occupancy under __launch_bounds__(256,4).
// KEY TRICK: a [64 rows x 64 keys] band slab of probs is a REGULAR 2D
// region: float index = r*512 + (K0+256) + c, 16B-aligned -> coalesced
// float4 staging into LDS [64][65] (pad -> conflict-free reads), with
// out-of-window elements zero-masked at stage time. V is broadcast-read
// from global (16KB/tile working set, L1-hot). Register double-buffer:
// next tile's loads are issued before compute, written to LDS after the
// barrier (T14 async-stage split).
// ---------------------------------------------------------------------------
__global__ __launch_bounds__(256, 4) void pv_banded(
    const float* __restrict__ probs, const float* __restrict__ v,
    float* __restrict__ ctx)
{
    __shared__ float pt[64 * 65];   // 16.6 KB P slab, padded stride

    const int bid  = blockIdx.x;
    const int bh   = bid >> 6;
    const int R    = (bid & 63) << 6;   // block's 64-row chunk
    const int tid  = threadIdx.x;
    const int lane = tid & 63;
    const int w    = tid >> 6;
    const int rb   = lane >> 3;         // row sub-block 0..7
    const int db   = lane & 7;          // d   sub-block 0..7
    const int rloc0 = w * 16 + rb * 2;  // local row pair base (0..62)

    const size_t pbase = (size_t)bh * S_LEN * WIN;
    const float4* v4 = reinterpret_cast<const float4*>(v + (size_t)bh * S_LEN * HDIM);

    // staging geometry: thread stages 4 float4; element i = tid + 256*s
    // -> local row ri = i>>4, float col c0 = (i&15)*4
    const int ri0 = tid >> 4;
    const int c0  = (tid & 15) << 2;

    float4 stg[4];

    auto stage_load = [&](int t) {
        const int K0 = R - WTOK + (t << 6);
        #pragma unroll
        for (int s = 0; s < 4; ++s) {
            int ri = ri0 + (s << 4);
            int r  = R + ri;                          // global row
            const float* p = probs + pbase + (size_t)r * 512 + (K0 + WTOK) + c0;
            float4 val = *reinterpret_cast<const float4*>(p);
            int k0 = K0 + c0;
            val.x = (k0     >= r - WTOK && k0     <= r + WTOK) ? val.x : 0.0f;
            val.y = (k0 + 1 >= r - WTOK && k0 + 1 <= r + WTOK) ? val.y : 0.0f;
            val.z = (k0 + 2 >= r - WTOK && k0 + 2 <= r + WTOK) ? val.z : 0.0f;
            val.w = (k0 + 3 >= r - WTOK && k0 + 3 <= r + WTOK) ? val.w : 0.0f;
            stg[s] = val;
        }
    };
    auto stage_write = [&]() {
        #pragma unroll
        for (int s = 0; s < 4; ++s) {
            int ri = ri0 + (s << 4);
            float* d = &pt[ri * 65 + c0];
            d[0] = stg[s].x; d[1] = stg[s].y; d[2] = stg[s].z; d[3] = stg[s].w;
        }
    };

    float acc[2][8];
    #pragma unroll
    for (int i = 0; i < 2; ++i)
        #pragma unroll
        for (int j = 0; j < 8; ++j) acc[i][j] = 0.0f;

    stage_load(0);
    stage_write();
    __syncthreads();

    for (int t = 0; t < 9; ++t) {
        if (t < 8) stage_load(t + 1);     // issue loads; waits sink to stage_write
        const int K0 = R - WTOK + (t << 6);

        #pragma unroll 8
        for (int kk = 0; kk < 64; ++kk) {
            int kc = min(max(K0 + kk, 0), S_LEN - 1);   // wave-uniform -> SALU
            const float4* vr = v4 + (size_t)kc * 16;
            float4 b0 = vr[db * 2];
            float4 b1 = vr[db * 2 + 1];
            float p0 = pt[rloc0 * 65 + kk];
            float p1 = pt[(rloc0 + 1) * 65 + kk];
            acc[0][0] = fmaf(p0, b0.x, acc[0][0]);
            acc[0][1] = fmaf(p0, b0.y, acc[0][1]);
            acc[0][2] = fmaf(p0, b0.z, acc[0][2]);
            acc[0][3] = fmaf(p0, b0.w, acc[0][3]);
            acc[0][4] = fmaf(p0, b1.x, acc[0][4]);
            acc[0][5] = fmaf(p0, b1.y, acc[0][5]);
            acc[0][6] = fmaf(p0, b1.z, acc[0][6]);
            acc[0][7] = fmaf(p0, b1.w, acc[0][7]);
            acc[1][0] = fmaf(p1, b0.x, acc[1][0]);
            acc[1][1] = fmaf(p1, b0.y, acc[1][1]);
            acc[1][2] = fmaf(p1, b0.z, acc[1][2]);
            acc[1][3] = fmaf(p1, b0.w, acc[1][3]);
            acc[1][4] = fmaf(p1, b1.x, acc[1][4]);
            acc[1][5] = fmaf(p1, b1.y, acc[1][5]);
            acc[1][6] = fmaf(p1, b1.z, acc[1][6]);
            acc[1][7] = fmaf(p1, b1.w, acc[1][7]);
        }
        __syncthreads();
        if (t < 8) {
            stage_write();
            __syncthreads();
        }
    }

    // write context: lane covers rows R+rloc0, R+rloc0+1, cols db*8..+7
    float* cb = ctx + (size_t)bh * S_LEN * HDIM;
    #pragma unroll
    for (int rr = 0; rr < 2; ++rr) {
        int r = R + rloc0 + rr;
        float4 o0 = make_float4(acc[rr][0], acc[rr][1], acc[rr][2], acc[rr][3]);
        float4 o1 = make_float4(acc[rr][4], acc[rr][5], acc[rr][6], acc[rr][7]);
        float4* o = reinterpret_cast<float4*>(cb + (size_t)r * HDIM + db * 8);
        o[0] = o0;
        o[1] = o1;
    }
}

// ---------------------------------------------------------------------------
extern "C" void kernel_launch(void* const* d_in, const int* in_sizes, int n_in,
                              void* d_out, int out_size, void* d_ws, size_t ws_size,
                              hipStream_t stream)
{
    const float* q = (const float*)d_in[0];
    const float* k = (const float*)d_in[1];
    const float* v = (const float*)d_in[2];
    (void)in_sizes; (void)n_in; (void)d_ws; (void)ws_size; (void)out_size;

    float* ctx   = (float*)d_out;               // [2,16,4096,64]
    float* probs = (float*)d_out + CTX_ELEMS;   // [32,4096,513]

    hipLaunchKernelGGL(qk_softmax_probs, dim3(NBH * 128), dim3(256), 0, stream,
                       q, k, probs);
    hipLaunchKernelGGL(pv_banded, dim3(NBH * 64), dim3(256), 0, stream,
                       probs, v, ctx);
}